// Round 2
// baseline (135.501 us; speedup 1.0000x reference)
//
#include <hip/hip_runtime.h>

// LePEAttention without softmax:  out = Q (K^T V) * (2*SCALE)
// q,k,v: (T=4, B=2, C=256, H=56, W=56) fp32. Windows: 2 of 56x28 (N=1568),
// heads=8, d=32. 128 problems: p = ((t*2+b)*2+win)*8+head.
//
// Kernel 1 (kv): Mpart[p][s] = K_s^T V_s over 112-position split s (14 splits).
//   Staged via global_load_lds (16B DMA, no VGPR round trip) in GLOBAL layout
//   [ch][112]; compute reads are b128 at uniform n0 -> 8 addr x 8-lane
//   broadcast = delivery-optimal, conflict-free.
// Kernel 2 (qm): M = SCALE2 * sum_s Mpart[p][s];  out = Q * M.
//   All 32 Q values preloaded per thread for full MLP.

#define HW 3136
#define WDIM 56
#define NPOS 1568
#define NPROB 128
#define SPLIT 14
#define PSPLIT 112            // positions per kv block
#define SCALE2 0.35355339059327373f   // 2 * 32^-0.5

typedef const __attribute__((address_space(1))) void gas_void;
typedef __attribute__((address_space(3))) void las_void;

// ---------------- Kernel 1: partial K^T V ----------------------------------
__global__ __launch_bounds__(256) void kv_kernel(const float* __restrict__ K,
                                                 const float* __restrict__ V,
                                                 float* __restrict__ Mpart) {
    // [K:32ch][112 pos] then [V:32ch][112 pos], fp32 -> 28672 B (5 blocks/CU)
    __shared__ float lds[2 * 32 * PSPLIT];

    const int blk = blockIdx.x;
    const int p   = blk / SPLIT;
    const int s   = blk - p * SPLIT;
    const int head = p & 7;
    const int win  = (p >> 3) & 1;
    const int b    = (p >> 4) & 1;
    const int t    = p >> 5;

    const size_t base = (size_t)((t * 2 + b) * 256 + head * 32) * HW;
    const float* __restrict__ Kb = K + base;
    const float* __restrict__ Vb = V + base;

    const int tid = threadIdx.x;
    const int l   = tid & 63;
    const int w   = tid >> 6;

    // ---- stage: 1792 16B-quads (2 tensors x 32 ch x 28 pos-quads).
    // Wave w, issue i covers quads q = (w*7+i)*64 + lane; LDS dest is linear
    // (wave-uniform base + lane*16), global src carries the per-lane mapping.
    #pragma unroll
    for (int i = 0; i < 7; ++i) {
        const int q   = (w * 7 + i) * 64 + l;
        const int isv = q >= 896 ? 1 : 0;     // wave-uniform (896 = 14*64)
        const int r   = q - isv * 896;
        const int ch  = r / 28;               // channel 0..31
        const int pq  = r - ch * 28;          // position quad 0..27
        const int n   = s * PSPLIT + pq * 4;  // global position, 4-aligned
        const int y   = n / 28;
        const int x   = n - y * 28;
        const float* src = (isv ? Vb : Kb)
                         + (size_t)ch * HW + y * WDIM + win * 28 + x;  // 16B-aligned
        float* dst = &lds[w * 1792 + i * 256];   // wave-uniform, = float offset q*4
        __builtin_amdgcn_global_load_lds((gas_void*)src, (las_void*)dst, 16, 0, 0);
    }
    __syncthreads();   // compiler emits s_waitcnt vmcnt(0) before barrier

    // ---- rank-1 accumulation: lane owns 4x4 tile of the 32x32 output.
    // Wave w covers positions 28w..28w+27 in steps of 4 (b128 on positions).
    const int dd0 = (l >> 3) * 4;
    const int de0 = (l & 7) * 4;

    float acc[4][4] = {{0.f}};
    #pragma unroll
    for (int j = 0; j < 7; ++j) {
        const int n0 = 28 * w + 4 * j;
        float4 ka[4], va[4];
        #pragma unroll
        for (int i = 0; i < 4; ++i) {
            ka[i] = *(const float4*)&lds[(dd0 + i) * PSPLIT + n0];
            va[i] = *(const float4*)&lds[32 * PSPLIT + (de0 + i) * PSPLIT + n0];
        }
        #pragma unroll
        for (int i = 0; i < 4; ++i)
            #pragma unroll
            for (int jj = 0; jj < 4; ++jj)
                acc[i][jj] += ka[i].x * va[jj].x + ka[i].y * va[jj].y
                            + ka[i].z * va[jj].z + ka[i].w * va[jj].w;
    }
    __syncthreads();

    // ---- reduce the 4 wave copies (overlay lds[0..4095])
    #pragma unroll
    for (int i = 0; i < 4; ++i)
        #pragma unroll
        for (int jj = 0; jj < 4; ++jj)
            lds[w * 1024 + (dd0 + i) * 32 + (de0 + jj)] = acc[i][jj];
    __syncthreads();

    const float4 r0 = *(const float4*)&lds[tid * 4];
    const float4 r1 = *(const float4*)&lds[1024 + tid * 4];
    const float4 r2 = *(const float4*)&lds[2048 + tid * 4];
    const float4 r3 = *(const float4*)&lds[3072 + tid * 4];
    float4 o;
    o.x = r0.x + r1.x + r2.x + r3.x;
    o.y = r0.y + r1.y + r2.y + r3.y;
    o.z = r0.z + r1.z + r2.z + r3.z;
    o.w = r0.w + r1.w + r2.w + r3.w;
    *(float4*)&Mpart[(size_t)blk * 1024 + tid * 4] = o;
}

// ---------------- Kernel 2: out = Q * (SCALE2 * sum_s Mpart) ----------------
__global__ __launch_bounds__(256) void qm_kernel(const float* __restrict__ Q,
                                                 const float* __restrict__ Mpart,
                                                 float* __restrict__ Out) {
    __shared__ float M[1024];
    const int blk = blockIdx.x;
    const int p   = blk / 7;
    const int c   = blk - p * 7;
    const int tid = threadIdx.x;

    // sum the 14 partials; fold in the scale
    const float* mp = Mpart + (size_t)p * SPLIT * 1024 + tid * 4;
    float4 sum = {0.f, 0.f, 0.f, 0.f};
    #pragma unroll
    for (int s = 0; s < SPLIT; ++s) {
        const float4 v = *(const float4*)&mp[s * 1024];
        sum.x += v.x; sum.y += v.y; sum.z += v.z; sum.w += v.w;
    }
    sum.x *= SCALE2; sum.y *= SCALE2; sum.z *= SCALE2; sum.w *= SCALE2;
    *(float4*)&M[tid * 4] = sum;
    __syncthreads();

    const int head = p & 7;
    const int win  = (p >> 3) & 1;
    const int b    = (p >> 4) & 1;
    const int t    = p >> 5;

    if (tid < 224) {
        const int n = c * 224 + tid;              // 7 blocks x 224 = 1568
        const int y = n / 28;
        const int x = n - y * 28;
        const size_t base = (size_t)((t * 2 + b) * 256 + head * 32) * HW
                          + y * WDIM + win * 28 + x;
        const float* __restrict__ Qb = Q + base;
        float* __restrict__ Ob = Out + base;

        // preload all 32 Q values -> 32 outstanding loads per thread
        float qv[32];
        #pragma unroll
        for (int dd = 0; dd < 32; ++dd)
            qv[dd] = Qb[(size_t)dd * HW];

        float acc[32] = {0.f};
        #pragma unroll 8
        for (int dd = 0; dd < 32; ++dd) {
            #pragma unroll
            for (int g = 0; g < 8; ++g) {
                const float4 m = *(const float4*)&M[dd * 32 + g * 4];  // broadcast b128
                acc[g * 4 + 0] += qv[dd] * m.x;
                acc[g * 4 + 1] += qv[dd] * m.y;
                acc[g * 4 + 2] += qv[dd] * m.z;
                acc[g * 4 + 3] += qv[dd] * m.w;
            }
        }
        #pragma unroll
        for (int de = 0; de < 32; ++de)
            Ob[(size_t)de * HW] = acc[de];
    }
}

extern "C" void kernel_launch(void* const* d_in, const int* in_sizes, int n_in,
                              void* d_out, int out_size, void* d_ws, size_t ws_size,
                              hipStream_t stream) {
    const float* q = (const float*)d_in[0];
    const float* k = (const float*)d_in[1];
    const float* v = (const float*)d_in[2];
    // d_in[3] is v_lamda == 1 (ignored)
    float* out   = (float*)d_out;
    float* Mpart = (float*)d_ws;   // 128*14*1024 floats = 7.34 MB, fully written by kv

    kv_kernel<<<NPROB * SPLIT, 256, 0, stream>>>(k, v, Mpart);
    qm_kernel<<<NPROB * 7, 256, 0, stream>>>(q, Mpart, out);
}

// Round 3
// 129.235 us; speedup vs baseline: 1.0485x; 1.0485x over previous
//
#include <hip/hip_runtime.h>

// LePEAttention without softmax:  out = Q (K^T V) * (2*SCALE)
// q,k,v: (T=4, B=2, C=256, H=56, W=56) fp32. Windows: 2 of 56x28 (N=1568),
// heads=8, d=32. 128 problems: p = ((t*2+b)*2+win)*8+head.
//
// Kernel 1 (kv): Mpart[p][s] = K_s^T V_s over 112-position split s (14 splits).
//   Staged via global_load_lds (16B DMA, linear LDS dest). LDS layout is
//   position-quad-major with a PERMUTED channel slot:
//     quad(tensor,ch,pq) -> tensor*896 + pq*32 + ((ch&3)<<3 | ch>>2)
//   so compute-phase b128 reads for the 8 dd0/de0 lane-groups land in 8
//   distinct 16B-granule classes -> conflict-free broadcast (the round-2
//   [ch][112] layout had 448B channel stride = 8-way bank conflicts).
//   Inner product uses v2f packed math -> v_pk_fma_f32.
// Kernel 2 (qm): M = SCALE2 * sum_s Mpart[p][s];  out = Q * M, packed math.

#define HW 3136
#define WDIM 56
#define NPROB 128
#define SPLIT 14
#define PSPLIT 112            // positions per kv block
#define SCALE2 0.35355339059327373f   // 2 * 32^-0.5

typedef const __attribute__((address_space(1))) void gas_void;
typedef __attribute__((address_space(3))) void las_void;
typedef float v2f __attribute__((ext_vector_type(2)));

// ---------------- Kernel 1: partial K^T V ----------------------------------
__global__ __launch_bounds__(256) void kv_kernel(const float* __restrict__ K,
                                                 const float* __restrict__ V,
                                                 float* __restrict__ Mpart) {
    // [tensor:2][pq:28][slot:32] 16B-quads, fp32 -> 28672 B (5 blocks/CU)
    __shared__ float lds[2 * 32 * PSPLIT];

    const int blk = blockIdx.x;
    const int p   = blk / SPLIT;
    const int s   = blk - p * SPLIT;
    const int head = p & 7;
    const int win  = (p >> 3) & 1;
    const int b    = (p >> 4) & 1;
    const int t    = p >> 5;

    const size_t base = (size_t)((t * 2 + b) * 256 + head * 32) * HW;
    const float* __restrict__ Kb = K + base;
    const float* __restrict__ Vb = V + base;

    const int tid = threadIdx.x;
    const int l   = tid & 63;
    const int w   = tid >> 6;

    // ---- stage: 1792 16B-quads. Linear LDS dest (wave-uniform base + lane*16);
    // the per-lane GLOBAL source realizes the permuted-slot layout.
    #pragma unroll
    for (int i = 0; i < 7; ++i) {
        const int q    = (w * 7 + i) * 64 + l;
        const int isv  = q >= 896 ? 1 : 0;    // wave-uniform (896 = 14*64)
        const int r    = q - isv * 896;
        const int pq   = r >> 5;              // position quad 0..27
        const int slot = r & 31;              // permuted channel slot
        const int ch   = ((slot & 7) << 2) + (slot >> 3);   // slot = g + 8*cc
        const int n    = s * PSPLIT + pq * 4; // global position, 4-aligned
        const int y    = n / 28;
        const int x    = n - y * 28;
        const float* src = (isv ? Vb : Kb)
                         + (size_t)ch * HW + y * WDIM + win * 28 + x;  // 16B-aligned
        float* dst = &lds[(w * 7 + i) * 256];   // wave-uniform
        __builtin_amdgcn_global_load_lds((gas_void*)src, (las_void*)dst, 16, 0, 0);
    }
    __syncthreads();   // compiler emits s_waitcnt vmcnt(0) before barrier

    // ---- rank-1 accumulation: lane owns 4x4 tile of the 32x32 output.
    // Wave w covers positions 28w..28w+27 in steps of 4.
    const int g = l >> 3;        // dd0 = 4g
    const int e = l & 7;         // de0 = 4e

    v2f acc2[4][4] = {};         // packed partial sums (x: even pos, y: odd pos)
    #pragma unroll
    for (int j = 0; j < 7; ++j) {
        const int rowb = (7 * w + j) * 128;   // float offset of this pq row
        float4 ka[4], va[4];
        #pragma unroll
        for (int i = 0; i < 4; ++i) {
            // granule class = g (ka) / e (va) mod 8 -> conflict-free
            ka[i] = *(const float4*)&lds[rowb + (g + 8 * i) * 4];
            va[i] = *(const float4*)&lds[3584 + rowb + (e + 8 * i) * 4];
        }
        #pragma unroll
        for (int i = 0; i < 4; ++i) {
            const v2f ka_lo = {ka[i].x, ka[i].y};
            const v2f ka_hi = {ka[i].z, ka[i].w};
            #pragma unroll
            for (int jj = 0; jj < 4; ++jj) {
                const v2f va_lo = {va[jj].x, va[jj].y};
                const v2f va_hi = {va[jj].z, va[jj].w};
                acc2[i][jj] += ka_lo * va_lo;   // v_pk_fma_f32
                acc2[i][jj] += ka_hi * va_hi;
            }
        }
    }
    __syncthreads();

    // ---- reduce the 4 wave copies (overlay lds[0..4095])
    const int dd0 = g * 4;
    const int de0 = e * 4;
    #pragma unroll
    for (int i = 0; i < 4; ++i)
        #pragma unroll
        for (int jj = 0; jj < 4; ++jj)
            lds[w * 1024 + (dd0 + i) * 32 + (de0 + jj)] = acc2[i][jj].x + acc2[i][jj].y;
    __syncthreads();

    const float4 r0 = *(const float4*)&lds[tid * 4];
    const float4 r1 = *(const float4*)&lds[1024 + tid * 4];
    const float4 r2 = *(const float4*)&lds[2048 + tid * 4];
    const float4 r3 = *(const float4*)&lds[3072 + tid * 4];
    float4 o;
    o.x = r0.x + r1.x + r2.x + r3.x;
    o.y = r0.y + r1.y + r2.y + r3.y;
    o.z = r0.z + r1.z + r2.z + r3.z;
    o.w = r0.w + r1.w + r2.w + r3.w;
    *(float4*)&Mpart[(size_t)blk * 1024 + tid * 4] = o;
}

// ---------------- Kernel 2: out = Q * (SCALE2 * sum_s Mpart) ----------------
__global__ __launch_bounds__(256) void qm_kernel(const float* __restrict__ Q,
                                                 const float* __restrict__ Mpart,
                                                 float* __restrict__ Out) {
    __shared__ float M[1024];
    const int blk = blockIdx.x;
    const int p   = blk / 7;
    const int c   = blk - p * 7;
    const int tid = threadIdx.x;

    // sum the 14 partials; fold in the scale
    const float* mp = Mpart + (size_t)p * SPLIT * 1024 + tid * 4;
    v2f s0 = {0.f, 0.f}, s1 = {0.f, 0.f};
    #pragma unroll
    for (int s = 0; s < SPLIT; ++s) {
        const float4 v = *(const float4*)&mp[s * 1024];
        const v2f vlo = {v.x, v.y};
        const v2f vhi = {v.z, v.w};
        s0 += vlo; s1 += vhi;
    }
    float4 sum;
    sum.x = s0.x * SCALE2; sum.y = s0.y * SCALE2;
    sum.z = s1.x * SCALE2; sum.w = s1.y * SCALE2;
    *(float4*)&M[tid * 4] = sum;
    __syncthreads();

    const int head = p & 7;
    const int win  = (p >> 3) & 1;
    const int b    = (p >> 4) & 1;
    const int t    = p >> 5;

    if (tid < 224) {
        const int n = c * 224 + tid;              // 7 blocks x 224 = 1568
        const int y = n / 28;
        const int x = n - y * 28;
        const size_t base = (size_t)((t * 2 + b) * 256 + head * 32) * HW
                          + y * WDIM + win * 28 + x;
        const float* __restrict__ Qb = Q + base;
        float* __restrict__ Ob = Out + base;

        // preload all 32 Q values -> 32 outstanding loads per thread
        float qv[32];
        #pragma unroll
        for (int dd = 0; dd < 32; ++dd)
            qv[dd] = Qb[(size_t)dd * HW];

        v2f acc2[16] = {};   // acc2[g*2+h] covers de = g*4 + h*2 + {0,1}
        #pragma unroll 8
        for (int dd = 0; dd < 32; ++dd) {
            const v2f qq = {qv[dd], qv[dd]};
            #pragma unroll
            for (int gg = 0; gg < 8; ++gg) {
                const float4 m = *(const float4*)&M[dd * 32 + gg * 4];  // broadcast b128
                const v2f mlo = {m.x, m.y};
                const v2f mhi = {m.z, m.w};
                acc2[gg * 2 + 0] += qq * mlo;   // v_pk_fma_f32
                acc2[gg * 2 + 1] += qq * mhi;
            }
        }
        #pragma unroll
        for (int gg = 0; gg < 8; ++gg) {
            Ob[(size_t)(gg * 4 + 0) * HW] = acc2[gg * 2 + 0].x;
            Ob[(size_t)(gg * 4 + 1) * HW] = acc2[gg * 2 + 0].y;
            Ob[(size_t)(gg * 4 + 2) * HW] = acc2[gg * 2 + 1].x;
            Ob[(size_t)(gg * 4 + 3) * HW] = acc2[gg * 2 + 1].y;
        }
    }
}

extern "C" void kernel_launch(void* const* d_in, const int* in_sizes, int n_in,
                              void* d_out, int out_size, void* d_ws, size_t ws_size,
                              hipStream_t stream) {
    const float* q = (const float*)d_in[0];
    const float* k = (const float*)d_in[1];
    const float* v = (const float*)d_in[2];
    // d_in[3] is v_lamda == 1 (ignored)
    float* out   = (float*)d_out;
    float* Mpart = (float*)d_ws;   // 128*14*1024 floats = 7.34 MB, fully written by kv

    kv_kernel<<<NPROB * SPLIT, 256, 0, stream>>>(k, v, Mpart);
    qm_kernel<<<NPROB * 7, 256, 0, stream>>>(q, Mpart, out);
}